// Round 1
// baseline (1081.239 us; speedup 1.0000x reference)
//
#include <hip/hip_runtime.h>

// rnn_lyapunov: B=64,T=2048,NIN=64,NH=512,NOUT=64
// Time-parallel chunked RNN, W=5 warmup (contraction ||A||~0.3).
// R9 (from R8): 8 waves x 4 A-tiles (64x64 output tile per wave) instead of
// 16 waves x 2 tiles -> per-step LDS h-read traffic halves (1.15->0.6 MiB/CU)
// and bank-conflict cycles scale down with it; A-L2 traffic / MFMA count
// unchanged. Head merged into all 8 waves (2 sub-units each, no imbalance),
// skipped during warmup. Bias folded into MFMA C-init. 2 waves/SIMD
// (__launch_bounds__(512,2), ~200 VGPR budget). 16x16x32 MFMA / f32x4 accs
// only (f32x16 shapes trigger a 400-600MB HBM anomaly - R4-R6).

#define T_LEN 2048
#define H_DIM 512
#define N_IN  64
#define N_OUT 64
#define L_CH  8
#define W_UP  5
#define S_FULL (W_UP + 8)        // 13 full steps (s=0..12) + final head-only
#define ST_H  520                // h_buf row stride (shorts): 16B-aligned
#define ST_U  72
#define K2f   2.8853900817779268f   // 2*log2(e), folded into Apk/WihPk/bias

typedef __attribute__((ext_vector_type(8))) short short8;   // 8 bf16 in 4 VGPRs
typedef __attribute__((ext_vector_type(4))) float f32x4;
typedef __attribute__((ext_vector_type(4))) unsigned u32x4;

__device__ __forceinline__ unsigned short f2bf(float f) {
  union { float f; unsigned u; } v; v.f = f;
  return (unsigned short)((v.u + 0x7FFFu + ((v.u >> 16) & 1u)) >> 16);  // RNE
}

#if __has_builtin(__builtin_amdgcn_cvt_pk_bf16_f32)
__device__ __forceinline__ unsigned pack2bf(float a, float b) {
  auto r = __builtin_amdgcn_cvt_pk_bf16_f32(a, b);
  unsigned u; __builtin_memcpy(&u, &r, 4);
  return u;
}
#else
__device__ __forceinline__ unsigned pack2bf(float a, float b) {
  return (unsigned)f2bf(a) | ((unsigned)f2bf(b) << 16);
}
#endif

#if __has_builtin(__builtin_amdgcn_exp2f)
#define EXP2(x) __builtin_amdgcn_exp2f(x)
#else
#define EXP2(x) exp2f(x)
#endif

// z = 2*log2(e)*x (prescale in weights): tanh(x) = 1 - 2/(2^z + 1)
__device__ __forceinline__ float tanh_z(float z) {
  float r = __builtin_amdgcn_rcpf(EXP2(z) + 1.f);
  return __builtin_fmaf(-2.f, r, 1.f);   // z->+inf: 1; z->-inf: -1
}

#define MFMA(a, b, acc) __builtin_amdgcn_mfma_f32_16x16x32_bf16(a, b, acc, 0, 0, 0)

// ---- pack weights into MFMA A-operand fragment layout ----------------------
// A-frag 16x16x32: lane L holds A[m = 16*mt + (L&15)][k = 32*kk + 8*(L>>4) + j]
// Apk  [kk=16][mt=32][lane][8] : K2*W_hh[m][k]*omega[k]^2
// WihPk[kk= 2][mt=32][lane][8] : K2*W_ih[m][k]
// WlinPk[kk=16][mt=4][lane][8] : W_lin[m][k]   (unscaled)
__global__ __launch_bounds__(256) void pack_kernel(
    const float* __restrict__ W_ih, const float* __restrict__ W_hh,
    const float* __restrict__ omega, const float* __restrict__ W_lin,
    unsigned short* __restrict__ Apk, unsigned short* __restrict__ WihPk,
    unsigned short* __restrict__ WlinPk)
{
  __shared__ unsigned short Lh[512][40];
  const int tid = threadIdx.x, bid = blockIdx.x;
  const int l32 = tid & 31, nr = tid >> 5;

  if (bid < 16) {                            // ---- A: kk = bid
    const int k0 = bid * 32;
    const float om = omega[k0 + l32];
    const float om2 = om * om * K2f;
    for (int n = nr; n < 512; n += 8)
      Lh[n][l32] = f2bf(W_hh[(size_t)n * 512 + k0 + l32] * om2);
    __syncthreads();
    const int mt = tid >> 3, lane0 = (tid & 7) * 8;
    unsigned short* dst = Apk + (size_t)bid * 16384 + (size_t)tid * 64;
    #pragma unroll
    for (int l = 0; l < 8; l++) {
      const int lane = lane0 + l, cc = lane & 15, qq = lane >> 4;
      *(short8*)(dst + l * 8) = *(const short8*)&Lh[mt * 16 + cc][qq * 8];
    }
  } else if (bid < 18) {                     // ---- W_ih: kk = bid-16
    const int kk = bid - 16, k0 = kk * 32;
    for (int n = nr; n < 512; n += 8)
      Lh[n][l32] = f2bf(W_ih[(size_t)n * 64 + k0 + l32] * K2f);
    __syncthreads();
    const int mt = tid >> 3, lane0 = (tid & 7) * 8;
    unsigned short* dst = WihPk + (size_t)kk * 16384 + (size_t)tid * 64;
    #pragma unroll
    for (int l = 0; l < 8; l++) {
      const int lane = lane0 + l, cc = lane & 15, qq = lane >> 4;
      *(short8*)(dst + l * 8) = *(const short8*)&Lh[mt * 16 + cc][qq * 8];
    }
  } else {                                   // ---- W_lin: kk = bid-18
    const int kk = bid - 18, k0 = kk * 32;
    for (int n = nr; n < 64; n += 8)
      Lh[n][l32] = f2bf(W_lin[(size_t)n * 512 + k0 + l32]);
    __syncthreads();
    const int mt = tid >> 6, lane = tid & 63, cc = lane & 15, qq = lane >> 4;
    unsigned short* dst = WlinPk + (size_t)kk * 2048 + (size_t)tid * 8;
    *(short8*)dst = *(const short8*)&Lh[mt * 16 + cc][qq * 8];
  }
}

// ---- main time-parallel recurrence kernel ----------------------------------
// 256 blocks (1 chunk, full batch M=64), 512 threads = 8 waves (1 block/CU,
// 2 waves/SIMD). Wave w owns hidden A-tiles {4w..4w+3} (64x64 output tile:
// each LDS h-fragment feeds 4-5 MFMAs vs 2-3 before -> LDS traffic halves).
// Head: wave w also owns W_lin tile (w>>1) for batch rows (w&1)*32..+31,
// active only for s > W_UP. One barrier per step.
__global__ __launch_bounds__(512, 2) void rnn_kernel(
    const float* __restrict__ u, const float* __restrict__ b_ih,
    const float* __restrict__ b_hh, const float* __restrict__ b_lin,
    const unsigned short* __restrict__ Apk,
    const unsigned short* __restrict__ WihPk,
    const unsigned short* __restrict__ WlinPk,
    float* __restrict__ out)
{
  __shared__ __align__(16) unsigned short h_buf[2][64][ST_H];  // 133,120 B
  __shared__ __align__(16) unsigned short u_buf[2][64][ST_U];  //  18,432 B

  const int tid = threadIdx.x;
  const int w = tid >> 6, lane = tid & 63, q = lane >> 4, c = lane & 15;
  const int t0 = blockIdx.x * L_CH;
  const int ht = w >> 1, bp = w & 1;     // head tile / batch-pair for this wave

  // biases in registers (prescaled by K2), folded into MFMA C-init
  f32x4 bsum[4];
  #pragma unroll
  for (int mt = 0; mt < 4; mt++) {
    const int n0 = (4 * w + mt) * 16 + q * 4;
    const f32x4 bs = *(const f32x4*)(b_ih + n0) + *(const f32x4*)(b_hh + n0);
    bsum[mt] = (f32x4){bs[0] * K2f, bs[1] * K2f, bs[2] * K2f, bs[3] * K2f};
  }
  const f32x4 blin4 = *(const f32x4*)(b_lin + ht * 16 + q * 4);

  for (int i = tid; i < 64 * ST_H / 2; i += 512) ((unsigned*)h_buf[0])[i] = 0;
  {    // stage u for step 0: tau(0) = max(t0 - W, 0); 8 floats/thread
    int t = t0 - W_UP; if (t < 0) t = 0;
    const int row = tid >> 3, cb = (tid & 7) * 8;
    const float* src = u + ((size_t)row * T_LEN + t) * N_IN + cb;
    u32x4 pk = {pack2bf(src[0], src[1]), pack2bf(src[2], src[3]),
                pack2bf(src[4], src[5]), pack2bf(src[6], src[7])};
    *(u32x4*)&u_buf[0][row][cb] = pk;
  }
  __syncthreads();

  f32x4 acc[4][4];
  const unsigned short* apA = Apk   + ((size_t)(4 * w) * 64 + lane) * 8;
  const unsigned short* wpA = WihPk + ((size_t)(4 * w) * 64 + lane) * 8;
  const unsigned short* lpA = WlinPk + ((size_t)ht * 64 + lane) * 8;

  for (int s = 0; s < S_FULL; s++) {
    const int cur = s & 1, nxt = cur ^ 1;

    // prefetch next step's u into registers (coalesced dwordx4 pairs)
    float up[8];
    {
      int tn = t0 - W_UP + s + 1;
      tn = tn < 0 ? 0 : (tn > T_LEN - 1 ? T_LEN - 1 : tn);
      const int row = tid >> 3, cb = (tid & 7) * 8;
      const float* src = u + ((size_t)row * T_LEN + tn) * N_IN + cb;
      #pragma unroll
      for (int j = 0; j < 8; j++) up[j] = src[j];
    }

    #pragma unroll
    for (int mt = 0; mt < 4; mt++)
      #pragma unroll
      for (int bt = 0; bt < 4; bt++)
        acc[mt][bt] = bsum[mt];           // bias as C-init

    // ---- A(L2) x h(LDS): K = 512; head accumulated when active ----
    if (s > W_UP) {
      f32x4 aL[2] = {blin4, blin4};
      #pragma unroll 2
      for (int kk = 0; kk < 16; kk++) {
        short8 hf[4];
        #pragma unroll
        for (int bt = 0; bt < 4; bt++)
          hf[bt] = *(const short8*)&h_buf[cur][bt * 16 + c][kk * 32 + q * 8];
        const short8 a0 = *(const short8*)(apA + (size_t)kk * 16384);
        const short8 a1 = *(const short8*)(apA + (size_t)kk * 16384 + 512);
        const short8 a2 = *(const short8*)(apA + (size_t)kk * 16384 + 1024);
        const short8 a3 = *(const short8*)(apA + (size_t)kk * 16384 + 1536);
        const short8 aw = *(const short8*)(lpA + (size_t)kk * 2048);
        #pragma unroll
        for (int bt = 0; bt < 4; bt++) {
          acc[0][bt] = MFMA(a0, hf[bt], acc[0][bt]);
          acc[1][bt] = MFMA(a1, hf[bt], acc[1][bt]);
          acc[2][bt] = MFMA(a2, hf[bt], acc[2][bt]);
          acc[3][bt] = MFMA(a3, hf[bt], acc[3][bt]);
        }
        aL[0] = MFMA(aw, hf[2 * bp],     aL[0]);
        aL[1] = MFMA(aw, hf[2 * bp + 1], aL[1]);
      }
      // head store: out_t = W_lin*h^s + b_lin, t = t0 + s - W_UP - 1
      const int t = t0 + s - W_UP - 1;
      #pragma unroll
      for (int i = 0; i < 2; i++) {
        const int bt = 2 * bp + i;
        float* op = out + ((size_t)(bt * 16 + c) * T_LEN + t) * N_OUT + ht * 16 + q * 4;
        *(f32x4*)op = aL[i];
      }
    } else {                               // warmup: no head work
      #pragma unroll 2
      for (int kk = 0; kk < 16; kk++) {
        short8 hf[4];
        #pragma unroll
        for (int bt = 0; bt < 4; bt++)
          hf[bt] = *(const short8*)&h_buf[cur][bt * 16 + c][kk * 32 + q * 8];
        const short8 a0 = *(const short8*)(apA + (size_t)kk * 16384);
        const short8 a1 = *(const short8*)(apA + (size_t)kk * 16384 + 512);
        const short8 a2 = *(const short8*)(apA + (size_t)kk * 16384 + 1024);
        const short8 a3 = *(const short8*)(apA + (size_t)kk * 16384 + 1536);
        #pragma unroll
        for (int bt = 0; bt < 4; bt++) {
          acc[0][bt] = MFMA(a0, hf[bt], acc[0][bt]);
          acc[1][bt] = MFMA(a1, hf[bt], acc[1][bt]);
          acc[2][bt] = MFMA(a2, hf[bt], acc[2][bt]);
          acc[3][bt] = MFMA(a3, hf[bt], acc[3][bt]);
        }
      }
    }

    // ---- + W_ih x u_t: K = 64, same accumulators ----
    #pragma unroll
    for (int kk = 0; kk < 2; kk++) {
      short8 uf[4];
      #pragma unroll
      for (int bt = 0; bt < 4; bt++)
        uf[bt] = *(const short8*)&u_buf[cur][bt * 16 + c][kk * 32 + q * 8];
      const short8 a0 = *(const short8*)(wpA + (size_t)kk * 16384);
      const short8 a1 = *(const short8*)(wpA + (size_t)kk * 16384 + 512);
      const short8 a2 = *(const short8*)(wpA + (size_t)kk * 16384 + 1024);
      const short8 a3 = *(const short8*)(wpA + (size_t)kk * 16384 + 1536);
      #pragma unroll
      for (int bt = 0; bt < 4; bt++) {
        acc[0][bt] = MFMA(a0, uf[bt], acc[0][bt]);
        acc[1][bt] = MFMA(a1, uf[bt], acc[1][bt]);
        acc[2][bt] = MFMA(a2, uf[bt], acc[2][bt]);
        acc[3][bt] = MFMA(a3, uf[bt], acc[3][bt]);
      }
    }

    // ---- epilogue: h_new = tanh_z(acc) -> h_buf[nxt] (b64 writes) ----
    #pragma unroll
    for (int mt = 0; mt < 4; mt++) {
      #pragma unroll
      for (int bt = 0; bt < 4; bt++) {
        const unsigned lo = pack2bf(tanh_z(acc[mt][bt][0]),
                                    tanh_z(acc[mt][bt][1]));
        const unsigned hi = pack2bf(tanh_z(acc[mt][bt][2]),
                                    tanh_z(acc[mt][bt][3]));
        unsigned* d = (unsigned*)&h_buf[nxt][bt * 16 + c][(4 * w + mt) * 16 + q * 4];
        d[0] = lo; d[1] = hi;
      }
    }
    {
      const int row = tid >> 3, cb = (tid & 7) * 8;
      u32x4 pk = {pack2bf(up[0], up[1]), pack2bf(up[2], up[3]),
                  pack2bf(up[4], up[5]), pack2bf(up[6], up[7])};
      *(u32x4*)&u_buf[nxt][row][cb] = pk;
    }
    __syncthreads();   // single barrier per step
  }

  // ---- final head-only step: all 8 waves, 2 sub-units each (h^13) ----
  {
    const int cur = S_FULL & 1;
    f32x4 aL[2] = {blin4, blin4};
    #pragma unroll 4
    for (int kk = 0; kk < 16; kk++) {
      const short8 aw = *(const short8*)(lpA + (size_t)kk * 2048);
      #pragma unroll
      for (int i = 0; i < 2; i++) {
        const short8 hf = *(const short8*)&h_buf[cur][(2 * bp + i) * 16 + c][kk * 32 + q * 8];
        aL[i] = MFMA(aw, hf, aL[i]);
      }
    }
    const int t = t0 + L_CH - 1;
    #pragma unroll
    for (int i = 0; i < 2; i++) {
      const int bt = 2 * bp + i;
      float* op = out + ((size_t)(bt * 16 + c) * T_LEN + t) * N_OUT + ht * 16 + q * 4;
      *(f32x4*)op = aL[i];
    }
  }
}

extern "C" void kernel_launch(void* const* d_in, const int* in_sizes, int n_in,
                              void* d_out, int out_size, void* d_ws, size_t ws_size,
                              hipStream_t stream) {
  const float* u     = (const float*)d_in[0];
  const float* W_ih  = (const float*)d_in[1];
  const float* W_hh  = (const float*)d_in[2];
  const float* b_ih  = (const float*)d_in[3];
  const float* b_hh  = (const float*)d_in[4];
  const float* omega = (const float*)d_in[5];
  const float* W_lin = (const float*)d_in[6];
  const float* b_lin = (const float*)d_in[7];
  float* out = (float*)d_out;

  unsigned short* Apk    = (unsigned short*)d_ws;                 // 512*512 bf16
  unsigned short* WihPk  = Apk + (size_t)H_DIM * H_DIM;           // 512*64
  unsigned short* WlinPk = WihPk + (size_t)H_DIM * N_IN;          // 64*512

  pack_kernel<<<34, 256, 0, stream>>>(W_ih, W_hh, omega, W_lin, Apk, WihPk, WlinPk);
  rnn_kernel<<<T_LEN / L_CH, 512, 0, stream>>>(u, b_ih, b_hh, b_lin,
                                               Apk, WihPk, WlinPk, out);
}

// Round 2
// 274.603 us; speedup vs baseline: 3.9375x; 3.9375x over previous
//
#include <hip/hip_runtime.h>

// rnn_lyapunov: B=64,T=2048,NIN=64,NH=512,NOUT=64
// Time-parallel chunked RNN, W=5 warmup (contraction ||A||~0.3).
// R10 (from R8 skeleton; R9 failed: runtime-indexed reg array -> scratch,
// 2 waves/SIMD): keep 16 waves / 4 per SIMD / 1024 threads, but retile each
// wave from 64batch x 32hidden to 32batch x 64hidden (acc[4][2], same 32 acc
// regs). Wave pair (2g,2g+1) shares one A-stream (L1 twin-hit); per-CU LDS
// h-read traffic halves (1.15 -> 0.59 MiB/step). Head on waves 0-7 (2/SIMD),
// ALL register-array indices compile-time. 16x16x32 MFMA / f32x4 accs only
// (f32x16 shapes trigger a 400-600MB HBM anomaly - R4-R6).

#define T_LEN 2048
#define H_DIM 512
#define N_IN  64
#define N_OUT 64
#define L_CH  8
#define W_UP  5
#define S_FULL (W_UP + 8)        // 13 full steps (s=0..12) + final head-only
#define ST_H  520                // h_buf row stride (shorts): 16B-aligned
#define ST_U  72
#define K2f   2.8853900817779268f   // 2*log2(e), folded into Apk/WihPk/bias

typedef __attribute__((ext_vector_type(8))) short short8;   // 8 bf16 in 4 VGPRs
typedef __attribute__((ext_vector_type(4))) float f32x4;

__device__ __forceinline__ unsigned short f2bf(float f) {
  union { float f; unsigned u; } v; v.f = f;
  return (unsigned short)((v.u + 0x7FFFu + ((v.u >> 16) & 1u)) >> 16);  // RNE
}

#if __has_builtin(__builtin_amdgcn_cvt_pk_bf16_f32)
__device__ __forceinline__ unsigned pack2bf(float a, float b) {
  auto r = __builtin_amdgcn_cvt_pk_bf16_f32(a, b);
  unsigned u; __builtin_memcpy(&u, &r, 4);
  return u;
}
#else
__device__ __forceinline__ unsigned pack2bf(float a, float b) {
  return (unsigned)f2bf(a) | ((unsigned)f2bf(b) << 16);
}
#endif

#if __has_builtin(__builtin_amdgcn_exp2f)
#define EXP2(x) __builtin_amdgcn_exp2f(x)
#else
#define EXP2(x) exp2f(x)
#endif

// z = 2*log2(e)*x (prescale in weights): tanh(x) = 1 - 2/(2^z + 1)
__device__ __forceinline__ float tanh_z(float z) {
  float r = __builtin_amdgcn_rcpf(EXP2(z) + 1.f);
  return __builtin_fmaf(-2.f, r, 1.f);   // z->+inf: 1; z->-inf: -1
}

#define MFMA(a, b, acc) __builtin_amdgcn_mfma_f32_16x16x32_bf16(a, b, acc, 0, 0, 0)

// ---- pack weights into MFMA A-operand fragment layout ----------------------
// A-frag 16x16x32: lane L holds A[m = 16*mt + (L&15)][k = 32*kk + 8*(L>>4) + j]
// Apk  [kk=16][mt=32][lane][8] : K2*W_hh[m][k]*omega[k]^2
// WihPk[kk= 2][mt=32][lane][8] : K2*W_ih[m][k]
// WlinPk[kk=16][mt=4][lane][8] : W_lin[m][k]   (unscaled)
__global__ __launch_bounds__(256) void pack_kernel(
    const float* __restrict__ W_ih, const float* __restrict__ W_hh,
    const float* __restrict__ omega, const float* __restrict__ W_lin,
    unsigned short* __restrict__ Apk, unsigned short* __restrict__ WihPk,
    unsigned short* __restrict__ WlinPk)
{
  __shared__ unsigned short Lh[512][40];
  const int tid = threadIdx.x, bid = blockIdx.x;
  const int l32 = tid & 31, nr = tid >> 5;

  if (bid < 16) {                            // ---- A: kk = bid
    const int k0 = bid * 32;
    const float om = omega[k0 + l32];
    const float om2 = om * om * K2f;
    for (int n = nr; n < 512; n += 8)
      Lh[n][l32] = f2bf(W_hh[(size_t)n * 512 + k0 + l32] * om2);
    __syncthreads();
    const int mt = tid >> 3, lane0 = (tid & 7) * 8;
    unsigned short* dst = Apk + (size_t)bid * 16384 + (size_t)tid * 64;
    #pragma unroll
    for (int l = 0; l < 8; l++) {
      const int lane = lane0 + l, cc = lane & 15, qq = lane >> 4;
      *(short8*)(dst + l * 8) = *(const short8*)&Lh[mt * 16 + cc][qq * 8];
    }
  } else if (bid < 18) {                     // ---- W_ih: kk = bid-16
    const int kk = bid - 16, k0 = kk * 32;
    for (int n = nr; n < 512; n += 8)
      Lh[n][l32] = f2bf(W_ih[(size_t)n * 64 + k0 + l32] * K2f);
    __syncthreads();
    const int mt = tid >> 3, lane0 = (tid & 7) * 8;
    unsigned short* dst = WihPk + (size_t)kk * 16384 + (size_t)tid * 64;
    #pragma unroll
    for (int l = 0; l < 8; l++) {
      const int lane = lane0 + l, cc = lane & 15, qq = lane >> 4;
      *(short8*)(dst + l * 8) = *(const short8*)&Lh[mt * 16 + cc][qq * 8];
    }
  } else {                                   // ---- W_lin: kk = bid-18
    const int kk = bid - 18, k0 = kk * 32;
    for (int n = nr; n < 64; n += 8)
      Lh[n][l32] = f2bf(W_lin[(size_t)n * 512 + k0 + l32]);
    __syncthreads();
    const int mt = tid >> 6, lane = tid & 63, cc = lane & 15, qq = lane >> 4;
    unsigned short* dst = WlinPk + (size_t)kk * 2048 + (size_t)tid * 8;
    *(short8*)dst = *(const short8*)&Lh[mt * 16 + cc][qq * 8];
  }
}

// ---- main time-parallel recurrence kernel ----------------------------------
// 256 blocks (1 chunk, full batch M=64), 1024 threads = 16 waves (1 block/CU,
// 4 waves/SIMD). Wave w: hidden-group hg=w>>1 (A-tiles 4hg..4hg+3), batch
// half bh=w&1 (rows bh*32..+31) -> 32x64 out tile, acc[4][2]. The pair
// (2g,2g+1) reads the SAME A-stream each step (L1 twin-hit). Each h-fragment
// read feeds 4 MFMAs (vs 2 in R8) -> LDS h-read traffic halves. Head: waves
// 0..7 (hg<4) also accumulate W_lin tile hg for their 2 batch-tiles; static
// indices only. One barrier per step.
__global__ __launch_bounds__(1024, 4) void rnn_kernel(
    const float* __restrict__ u, const float* __restrict__ b_ih,
    const float* __restrict__ b_hh, const float* __restrict__ b_lin,
    const unsigned short* __restrict__ Apk,
    const unsigned short* __restrict__ WihPk,
    const unsigned short* __restrict__ WlinPk,
    float* __restrict__ out)
{
  __shared__ __align__(16) unsigned short h_buf[2][64][ST_H];  // 133,120 B
  __shared__ __align__(16) unsigned short u_buf[2][64][ST_U];  //  18,432 B

  const int tid = threadIdx.x;
  const int w = tid >> 6, lane = tid & 63, q = lane >> 4, c = lane & 15;
  const int t0 = blockIdx.x * L_CH;
  const int hg = w >> 1, bh = w & 1;       // hidden-group / batch-half
  const bool hw = (hg < 4);                // head wave?
  const int ht = hg & 3;                   // head W_lin tile (valid when hw)
  const int r0 = 2 * bh;                   // first batch-tile index (0 or 2)

  // biases in registers (prescaled by K2); b_lin raw
  f32x4 bsum[4];
  #pragma unroll
  for (int mt = 0; mt < 4; mt++) {
    const int n0 = (4 * hg + mt) * 16 + q * 4;
    const f32x4 bs = *(const f32x4*)(b_ih + n0) + *(const f32x4*)(b_hh + n0);
    bsum[mt] = (f32x4){bs[0] * K2f, bs[1] * K2f, bs[2] * K2f, bs[3] * K2f};
  }
  const f32x4 blin4 = *(const f32x4*)(b_lin + ht * 16 + q * 4);

  for (int i = tid; i < 64 * ST_H / 2; i += 1024) ((unsigned*)h_buf[0])[i] = 0;
  {    // stage u for step 0: tau(0) = max(t0 - W, 0)
    int t = t0 - W_UP; if (t < 0) t = 0;
    const int row = tid >> 4, cb = (tid & 15) * 4;
    const float* src = u + ((size_t)row * T_LEN + t) * N_IN + cb;
    unsigned* d = (unsigned*)&u_buf[0][row][cb];
    d[0] = pack2bf(src[0], src[1]); d[1] = pack2bf(src[2], src[3]);
  }
  __syncthreads();

  f32x4 acc[4][2];
  const unsigned short* apA = Apk    + ((size_t)(4 * hg) * 64 + lane) * 8;
  const unsigned short* wpA = WihPk  + ((size_t)(4 * hg) * 64 + lane) * 8;
  const unsigned short* lpA = WlinPk + ((size_t)ht * 64 + lane) * 8;

  for (int s = 0; s < S_FULL; s++) {
    const int cur = s & 1, nxt = cur ^ 1;

    // prefetch next step's u into registers (coalesced dwordx4)
    float up0, up1, up2, up3;
    {
      int tn = t0 - W_UP + s + 1;
      tn = tn < 0 ? 0 : (tn > T_LEN - 1 ? T_LEN - 1 : tn);
      const int row = tid >> 4, cb = (tid & 15) * 4;
      const float* src = u + ((size_t)row * T_LEN + tn) * N_IN + cb;
      up0 = src[0]; up1 = src[1]; up2 = src[2]; up3 = src[3];
    }

    #pragma unroll
    for (int mt = 0; mt < 4; mt++)
      #pragma unroll
      for (int bt = 0; bt < 2; bt++)
        acc[mt][bt] = (f32x4){0.f, 0.f, 0.f, 0.f};

    // ---- A(L2/L1) x h(LDS): K = 512; head waves also accumulate W_lin x h --
    if (hw) {
      f32x4 aL[2];
      aL[0] = (f32x4){0.f, 0.f, 0.f, 0.f};
      aL[1] = (f32x4){0.f, 0.f, 0.f, 0.f};
      #pragma unroll 4
      for (int kk = 0; kk < 16; kk++) {
        short8 hf[2];
        #pragma unroll
        for (int bt = 0; bt < 2; bt++)
          hf[bt] = *(const short8*)&h_buf[cur][(r0 + bt) * 16 + c][kk * 32 + q * 8];
        const short8 a0 = *(const short8*)(apA + (size_t)kk * 16384);
        const short8 a1 = *(const short8*)(apA + (size_t)kk * 16384 + 512);
        const short8 a2 = *(const short8*)(apA + (size_t)kk * 16384 + 1024);
        const short8 a3 = *(const short8*)(apA + (size_t)kk * 16384 + 1536);
        const short8 aw = *(const short8*)(lpA + (size_t)kk * 2048);
        #pragma unroll
        for (int bt = 0; bt < 2; bt++) {
          acc[0][bt] = MFMA(a0, hf[bt], acc[0][bt]);
          acc[1][bt] = MFMA(a1, hf[bt], acc[1][bt]);
          acc[2][bt] = MFMA(a2, hf[bt], acc[2][bt]);
          acc[3][bt] = MFMA(a3, hf[bt], acc[3][bt]);
          aL[bt]     = MFMA(aw, hf[bt], aL[bt]);
        }
      }
      // head store: out_t = W_lin*h^s + b_lin, t = t0 + s - W_UP - 1
      if (s > W_UP) {
        const int t = t0 + s - W_UP - 1;
        #pragma unroll
        for (int bt = 0; bt < 2; bt++) {
          const f32x4 res = aL[bt] + blin4;
          float* op = out + ((size_t)((r0 + bt) * 16 + c) * T_LEN + t) * N_OUT + ht * 16 + q * 4;
          *(f32x4*)op = res;
        }
      }
    } else {
      #pragma unroll 4
      for (int kk = 0; kk < 16; kk++) {
        short8 hf[2];
        #pragma unroll
        for (int bt = 0; bt < 2; bt++)
          hf[bt] = *(const short8*)&h_buf[cur][(r0 + bt) * 16 + c][kk * 32 + q * 8];
        const short8 a0 = *(const short8*)(apA + (size_t)kk * 16384);
        const short8 a1 = *(const short8*)(apA + (size_t)kk * 16384 + 512);
        const short8 a2 = *(const short8*)(apA + (size_t)kk * 16384 + 1024);
        const short8 a3 = *(const short8*)(apA + (size_t)kk * 16384 + 1536);
        #pragma unroll
        for (int bt = 0; bt < 2; bt++) {
          acc[0][bt] = MFMA(a0, hf[bt], acc[0][bt]);
          acc[1][bt] = MFMA(a1, hf[bt], acc[1][bt]);
          acc[2][bt] = MFMA(a2, hf[bt], acc[2][bt]);
          acc[3][bt] = MFMA(a3, hf[bt], acc[3][bt]);
        }
      }
    }

    // ---- + W_ih x u_t: K = 64, same accumulators (all waves) ----
    {
      #pragma unroll
      for (int kk = 0; kk < 2; kk++) {
        short8 uf[2];
        #pragma unroll
        for (int bt = 0; bt < 2; bt++)
          uf[bt] = *(const short8*)&u_buf[cur][(r0 + bt) * 16 + c][kk * 32 + q * 8];
        const short8 a0 = *(const short8*)(wpA + (size_t)kk * 16384);
        const short8 a1 = *(const short8*)(wpA + (size_t)kk * 16384 + 512);
        const short8 a2 = *(const short8*)(wpA + (size_t)kk * 16384 + 1024);
        const short8 a3 = *(const short8*)(wpA + (size_t)kk * 16384 + 1536);
        #pragma unroll
        for (int bt = 0; bt < 2; bt++) {
          acc[0][bt] = MFMA(a0, uf[bt], acc[0][bt]);
          acc[1][bt] = MFMA(a1, uf[bt], acc[1][bt]);
          acc[2][bt] = MFMA(a2, uf[bt], acc[2][bt]);
          acc[3][bt] = MFMA(a3, uf[bt], acc[3][bt]);
        }
      }
    }

    // ---- epilogue: h_new = tanh_z(acc + bias) -> h_buf[nxt] (b64 writes) ----
    #pragma unroll
    for (int mt = 0; mt < 4; mt++) {
      #pragma unroll
      for (int bt = 0; bt < 2; bt++) {
        const unsigned lo = pack2bf(tanh_z(acc[mt][bt][0] + bsum[mt][0]),
                                    tanh_z(acc[mt][bt][1] + bsum[mt][1]));
        const unsigned hi = pack2bf(tanh_z(acc[mt][bt][2] + bsum[mt][2]),
                                    tanh_z(acc[mt][bt][3] + bsum[mt][3]));
        unsigned* d = (unsigned*)&h_buf[nxt][(r0 + bt) * 16 + c][(4 * hg + mt) * 16 + q * 4];
        d[0] = lo; d[1] = hi;
      }
    }
    {
      const int row = tid >> 4, cb = (tid & 15) * 4;
      unsigned* d = (unsigned*)&u_buf[nxt][row][cb];
      d[0] = pack2bf(up0, up1); d[1] = pack2bf(up2, up3);
    }
    __syncthreads();   // single barrier per step
  }

  // ---- final head-only step: waves 0..7, 2 batch-tiles each (h^13) ----
  if (hw) {
    const int cur = S_FULL & 1;
    f32x4 aL[2];
    aL[0] = (f32x4){0.f, 0.f, 0.f, 0.f};
    aL[1] = (f32x4){0.f, 0.f, 0.f, 0.f};
    #pragma unroll 4
    for (int kk = 0; kk < 16; kk++) {
      const short8 aw = *(const short8*)(lpA + (size_t)kk * 2048);
      #pragma unroll
      for (int bt = 0; bt < 2; bt++) {
        const short8 hf = *(const short8*)&h_buf[cur][(r0 + bt) * 16 + c][kk * 32 + q * 8];
        aL[bt] = MFMA(aw, hf, aL[bt]);
      }
    }
    const int t = t0 + L_CH - 1;
    #pragma unroll
    for (int bt = 0; bt < 2; bt++) {
      const f32x4 res = aL[bt] + blin4;
      float* op = out + ((size_t)((r0 + bt) * 16 + c) * T_LEN + t) * N_OUT + ht * 16 + q * 4;
      *(f32x4*)op = res;
    }
  }
}

extern "C" void kernel_launch(void* const* d_in, const int* in_sizes, int n_in,
                              void* d_out, int out_size, void* d_ws, size_t ws_size,
                              hipStream_t stream) {
  const float* u     = (const float*)d_in[0];
  const float* W_ih  = (const float*)d_in[1];
  const float* W_hh  = (const float*)d_in[2];
  const float* b_ih  = (const float*)d_in[3];
  const float* b_hh  = (const float*)d_in[4];
  const float* omega = (const float*)d_in[5];
  const float* W_lin = (const float*)d_in[6];
  const float* b_lin = (const float*)d_in[7];
  float* out = (float*)d_out;

  unsigned short* Apk    = (unsigned short*)d_ws;                 // 512*512 bf16
  unsigned short* WihPk  = Apk + (size_t)H_DIM * H_DIM;           // 512*64
  unsigned short* WlinPk = WihPk + (size_t)H_DIM * N_IN;          // 64*512

  pack_kernel<<<34, 256, 0, stream>>>(W_ih, W_hh, omega, W_lin, Apk, WihPk, WlinPk);
  rnn_kernel<<<T_LEN / L_CH, 1024, 0, stream>>>(u, b_ih, b_hh, b_lin,
                                                Apk, WihPk, WlinPk, out);
}

// Round 3
// 233.760 us; speedup vs baseline: 4.6254x; 1.1747x over previous
//
#include <hip/hip_runtime.h>

// rnn_lyapunov: B=64,T=2048,NIN=64,NH=512,NOUT=64
// Time-parallel chunked RNN, W=5 warmup (contraction ||A||~0.3).
// R11 (R8 skeleton + warmup amortization). R9/R10 lessons: LDS conflicts are
// NOT the critical path (halved them twice, never helped); A-stream L2 volume
// must stay at 512KB per block-step (R10's 2x A-requests -> FETCH doubled,
// MfmaUtil 29%, +50us). This round: L_CH 8->16 with batch-split (M=32/block,
// 2 blocks per t-chunk, bid = bh*128+chunk so both halves share an XCD L2 for
// the u window). 256 blocks x 22 half-steps = 21% less MFMA work than
// 256 x 14 full-steps. Per-wave tiling identical to R8 (2 hidden tiles,
// A element read once per block-step). Head on waves 0-3 (one per SIMD,
// 2 batch-tiles each, static reg indices). 16x16x32 MFMA / f32x4 accs only
// (f32x16 shapes trigger a 400-600MB HBM anomaly - R4-R6).

#define T_LEN 2048
#define H_DIM 512
#define N_IN  64
#define N_OUT 64
#define L_CH  16
#define M_B   32                 // batch rows per block (batch-split 2)
#define W_UP  5
#define S_FULL (W_UP + L_CH)     // 21 full steps (s=0..20) + final head-only
#define ST_H  520                // h_buf row stride (shorts): 16B-aligned
#define ST_U  72
#define K2f   2.8853900817779268f   // 2*log2(e), folded into Apk/WihPk/bias

typedef __attribute__((ext_vector_type(8))) short short8;   // 8 bf16 in 4 VGPRs
typedef __attribute__((ext_vector_type(4))) float f32x4;

__device__ __forceinline__ unsigned short f2bf(float f) {
  union { float f; unsigned u; } v; v.f = f;
  return (unsigned short)((v.u + 0x7FFFu + ((v.u >> 16) & 1u)) >> 16);  // RNE
}

#if __has_builtin(__builtin_amdgcn_cvt_pk_bf16_f32)
__device__ __forceinline__ unsigned pack2bf(float a, float b) {
  auto r = __builtin_amdgcn_cvt_pk_bf16_f32(a, b);
  unsigned u; __builtin_memcpy(&u, &r, 4);
  return u;
}
#else
__device__ __forceinline__ unsigned pack2bf(float a, float b) {
  return (unsigned)f2bf(a) | ((unsigned)f2bf(b) << 16);
}
#endif

#if __has_builtin(__builtin_amdgcn_exp2f)
#define EXP2(x) __builtin_amdgcn_exp2f(x)
#else
#define EXP2(x) exp2f(x)
#endif

// z = 2*log2(e)*x (prescale in weights): tanh(x) = 1 - 2/(2^z + 1)
__device__ __forceinline__ float tanh_z(float z) {
  float r = __builtin_amdgcn_rcpf(EXP2(z) + 1.f);
  return __builtin_fmaf(-2.f, r, 1.f);   // z->+inf: 1; z->-inf: -1
}

#define MFMA(a, b, acc) __builtin_amdgcn_mfma_f32_16x16x32_bf16(a, b, acc, 0, 0, 0)

// ---- pack weights into MFMA A-operand fragment layout ----------------------
// A-frag 16x16x32: lane L holds A[m = 16*mt + (L&15)][k = 32*kk + 8*(L>>4) + j]
// Apk  [kk=16][mt=32][lane][8] : K2*W_hh[m][k]*omega[k]^2
// WihPk[kk= 2][mt=32][lane][8] : K2*W_ih[m][k]
// WlinPk[kk=16][mt=4][lane][8] : W_lin[m][k]   (unscaled)
__global__ __launch_bounds__(256) void pack_kernel(
    const float* __restrict__ W_ih, const float* __restrict__ W_hh,
    const float* __restrict__ omega, const float* __restrict__ W_lin,
    unsigned short* __restrict__ Apk, unsigned short* __restrict__ WihPk,
    unsigned short* __restrict__ WlinPk)
{
  __shared__ unsigned short Lh[512][40];
  const int tid = threadIdx.x, bid = blockIdx.x;
  const int l32 = tid & 31, nr = tid >> 5;

  if (bid < 16) {                            // ---- A: kk = bid
    const int k0 = bid * 32;
    const float om = omega[k0 + l32];
    const float om2 = om * om * K2f;
    for (int n = nr; n < 512; n += 8)
      Lh[n][l32] = f2bf(W_hh[(size_t)n * 512 + k0 + l32] * om2);
    __syncthreads();
    const int mt = tid >> 3, lane0 = (tid & 7) * 8;
    unsigned short* dst = Apk + (size_t)bid * 16384 + (size_t)tid * 64;
    #pragma unroll
    for (int l = 0; l < 8; l++) {
      const int lane = lane0 + l, cc = lane & 15, qq = lane >> 4;
      *(short8*)(dst + l * 8) = *(const short8*)&Lh[mt * 16 + cc][qq * 8];
    }
  } else if (bid < 18) {                     // ---- W_ih: kk = bid-16
    const int kk = bid - 16, k0 = kk * 32;
    for (int n = nr; n < 512; n += 8)
      Lh[n][l32] = f2bf(W_ih[(size_t)n * 64 + k0 + l32] * K2f);
    __syncthreads();
    const int mt = tid >> 3, lane0 = (tid & 7) * 8;
    unsigned short* dst = WihPk + (size_t)kk * 16384 + (size_t)tid * 64;
    #pragma unroll
    for (int l = 0; l < 8; l++) {
      const int lane = lane0 + l, cc = lane & 15, qq = lane >> 4;
      *(short8*)(dst + l * 8) = *(const short8*)&Lh[mt * 16 + cc][qq * 8];
    }
  } else {                                   // ---- W_lin: kk = bid-18
    const int kk = bid - 18, k0 = kk * 32;
    for (int n = nr; n < 64; n += 8)
      Lh[n][l32] = f2bf(W_lin[(size_t)n * 512 + k0 + l32]);
    __syncthreads();
    const int mt = tid >> 6, lane = tid & 63, cc = lane & 15, qq = lane >> 4;
    unsigned short* dst = WlinPk + (size_t)kk * 2048 + (size_t)tid * 8;
    *(short8*)dst = *(const short8*)&Lh[mt * 16 + cc][qq * 8];
  }
}

// ---- main time-parallel recurrence kernel ----------------------------------
// 256 blocks = 128 t-chunks x 2 batch-halves (bid = bh*128 + chunk so pair
// shares an XCD). 1024 threads = 16 waves (1 block/CU, 4 waves/SIMD).
// Wave w owns hidden A-tiles {2w, 2w+1} (R8 tiling: A element read once per
// block-step), batch tiles 0-1 (this block's 32 rows), acc[2][2].
// Waves 0-3 also own W_lin tile w (both batch tiles, static indices).
// One barrier per step.
__global__ __launch_bounds__(1024, 4) void rnn_kernel(
    const float* __restrict__ u, const float* __restrict__ b_ih,
    const float* __restrict__ b_hh, const float* __restrict__ b_lin,
    const unsigned short* __restrict__ Apk,
    const unsigned short* __restrict__ WihPk,
    const unsigned short* __restrict__ WlinPk,
    float* __restrict__ out)
{
  __shared__ __align__(16) unsigned short h_buf[2][M_B][ST_H];  // 66,560 B
  __shared__ __align__(16) unsigned short u_buf[2][M_B][ST_U];  //  9,216 B

  const int tid = threadIdx.x;
  const int w = tid >> 6, lane = tid & 63, q = lane >> 4, c = lane & 15;
  const int bh = blockIdx.x >> 7;            // batch half (0/1)
  const int t0 = (blockIdx.x & 127) * L_CH;  // t-chunk origin
  const int B0 = bh * M_B;                   // global batch row base
  const bool hw = (w < 4);                   // head wave (one per SIMD)
  const int lt = w & 3;                      // head W_lin tile (valid when hw)

  // biases in registers (prescaled by K2); b_lin raw
  f32x4 bsum[2];
  #pragma unroll
  for (int mt = 0; mt < 2; mt++) {
    const int n0 = (2 * w + mt) * 16 + q * 4;
    const f32x4 bs = *(const f32x4*)(b_ih + n0) + *(const f32x4*)(b_hh + n0);
    bsum[mt] = (f32x4){bs[0] * K2f, bs[1] * K2f, bs[2] * K2f, bs[3] * K2f};
  }
  const f32x4 blin4 = *(const f32x4*)(b_lin + lt * 16 + q * 4);

  for (int i = tid; i < M_B * ST_H / 2; i += 1024) ((unsigned*)h_buf[0])[i] = 0;
  {    // stage u for step 0: tau(0) = max(t0 - W, 0); 2 floats/thread
    int t = t0 - W_UP; if (t < 0) t = 0;
    const int row = tid >> 5, cb = (tid & 31) * 2;
    const float* src = u + ((size_t)(B0 + row) * T_LEN + t) * N_IN + cb;
    *(unsigned*)&u_buf[0][row][cb] = pack2bf(src[0], src[1]);
  }
  __syncthreads();

  f32x4 acc[2][2];
  const unsigned short* apA = Apk    + ((size_t)(2 * w) * 64 + lane) * 8;
  const unsigned short* wpA = WihPk  + ((size_t)(2 * w) * 64 + lane) * 8;
  const unsigned short* lpA = WlinPk + ((size_t)lt * 64 + lane) * 8;

  for (int s = 0; s < S_FULL; s++) {
    const int cur = s & 1, nxt = cur ^ 1;

    // prefetch next step's u into registers (coalesced)
    float up0, up1;
    {
      int tn = t0 - W_UP + s + 1;
      tn = tn < 0 ? 0 : (tn > T_LEN - 1 ? T_LEN - 1 : tn);
      const int row = tid >> 5, cb = (tid & 31) * 2;
      const float* src = u + ((size_t)(B0 + row) * T_LEN + tn) * N_IN + cb;
      up0 = src[0]; up1 = src[1];
    }

    #pragma unroll
    for (int mt = 0; mt < 2; mt++)
      #pragma unroll
      for (int bt = 0; bt < 2; bt++)
        acc[mt][bt] = (f32x4){0.f, 0.f, 0.f, 0.f};

    // ---- A(L2) x h(LDS): K = 512; head waves also accumulate W_lin x h ----
    if (hw) {
      f32x4 aL[2];
      aL[0] = (f32x4){0.f, 0.f, 0.f, 0.f};
      aL[1] = (f32x4){0.f, 0.f, 0.f, 0.f};
      #pragma unroll 4
      for (int kk = 0; kk < 16; kk++) {
        short8 hf[2];
        #pragma unroll
        for (int bt = 0; bt < 2; bt++)
          hf[bt] = *(const short8*)&h_buf[cur][bt * 16 + c][kk * 32 + q * 8];
        const short8 a0 = *(const short8*)(apA + (size_t)kk * 16384);
        const short8 a1 = *(const short8*)(apA + (size_t)kk * 16384 + 512);
        const short8 aw = *(const short8*)(lpA + (size_t)kk * 2048);
        #pragma unroll
        for (int bt = 0; bt < 2; bt++) {
          acc[0][bt] = MFMA(a0, hf[bt], acc[0][bt]);
          acc[1][bt] = MFMA(a1, hf[bt], acc[1][bt]);
          aL[bt]     = MFMA(aw, hf[bt], aL[bt]);
        }
      }
      // head store: out_t = W_lin*h^s + b_lin, t = t0 + s - W_UP - 1
      if (s > W_UP) {
        const int t = t0 + s - W_UP - 1;
        #pragma unroll
        for (int bt = 0; bt < 2; bt++) {
          const f32x4 res = aL[bt] + blin4;
          float* op = out + ((size_t)(B0 + bt * 16 + c) * T_LEN + t) * N_OUT + lt * 16 + q * 4;
          *(f32x4*)op = res;
        }
      }
    } else {
      #pragma unroll 4
      for (int kk = 0; kk < 16; kk++) {
        short8 hf[2];
        #pragma unroll
        for (int bt = 0; bt < 2; bt++)
          hf[bt] = *(const short8*)&h_buf[cur][bt * 16 + c][kk * 32 + q * 8];
        const short8 a0 = *(const short8*)(apA + (size_t)kk * 16384);
        const short8 a1 = *(const short8*)(apA + (size_t)kk * 16384 + 512);
        #pragma unroll
        for (int bt = 0; bt < 2; bt++) {
          acc[0][bt] = MFMA(a0, hf[bt], acc[0][bt]);
          acc[1][bt] = MFMA(a1, hf[bt], acc[1][bt]);
        }
      }
    }

    // ---- + W_ih x u_t: K = 64, same accumulators (all waves) ----
    {
      #pragma unroll
      for (int kk = 0; kk < 2; kk++) {
        short8 uf[2];
        #pragma unroll
        for (int bt = 0; bt < 2; bt++)
          uf[bt] = *(const short8*)&u_buf[cur][bt * 16 + c][kk * 32 + q * 8];
        const short8 a0 = *(const short8*)(wpA + (size_t)kk * 16384);
        const short8 a1 = *(const short8*)(wpA + (size_t)kk * 16384 + 512);
        #pragma unroll
        for (int bt = 0; bt < 2; bt++) {
          acc[0][bt] = MFMA(a0, uf[bt], acc[0][bt]);
          acc[1][bt] = MFMA(a1, uf[bt], acc[1][bt]);
        }
      }
    }

    // ---- epilogue: h_new = tanh_z(acc + bias) -> h_buf[nxt] (b64 writes) ----
    #pragma unroll
    for (int mt = 0; mt < 2; mt++) {
      #pragma unroll
      for (int bt = 0; bt < 2; bt++) {
        const unsigned lo = pack2bf(tanh_z(acc[mt][bt][0] + bsum[mt][0]),
                                    tanh_z(acc[mt][bt][1] + bsum[mt][1]));
        const unsigned hi = pack2bf(tanh_z(acc[mt][bt][2] + bsum[mt][2]),
                                    tanh_z(acc[mt][bt][3] + bsum[mt][3]));
        unsigned* d = (unsigned*)&h_buf[nxt][bt * 16 + c][(2 * w + mt) * 16 + q * 4];
        d[0] = lo; d[1] = hi;
      }
    }
    {
      const int row = tid >> 5, cb = (tid & 31) * 2;
      *(unsigned*)&u_buf[nxt][row][cb] = pack2bf(up0, up1);
    }
    __syncthreads();   // single barrier per step
  }

  // ---- final head-only step: waves 0-3 consume h^21 (buf [S_FULL&1]) ----
  if (hw) {
    const int cur = S_FULL & 1;
    f32x4 aL[2];
    aL[0] = (f32x4){0.f, 0.f, 0.f, 0.f};
    aL[1] = (f32x4){0.f, 0.f, 0.f, 0.f};
    #pragma unroll 4
    for (int kk = 0; kk < 16; kk++) {
      const short8 aw = *(const short8*)(lpA + (size_t)kk * 2048);
      #pragma unroll
      for (int bt = 0; bt < 2; bt++) {
        const short8 hf = *(const short8*)&h_buf[cur][bt * 16 + c][kk * 32 + q * 8];
        aL[bt] = MFMA(aw, hf, aL[bt]);
      }
    }
    const int t = t0 + L_CH - 1;
    #pragma unroll
    for (int bt = 0; bt < 2; bt++) {
      const f32x4 res = aL[bt] + blin4;
      float* op = out + ((size_t)(B0 + bt * 16 + c) * T_LEN + t) * N_OUT + lt * 16 + q * 4;
      *(f32x4*)op = res;
    }
  }
}

extern "C" void kernel_launch(void* const* d_in, const int* in_sizes, int n_in,
                              void* d_out, int out_size, void* d_ws, size_t ws_size,
                              hipStream_t stream) {
  const float* u     = (const float*)d_in[0];
  const float* W_ih  = (const float*)d_in[1];
  const float* W_hh  = (const float*)d_in[2];
  const float* b_ih  = (const float*)d_in[3];
  const float* b_hh  = (const float*)d_in[4];
  const float* omega = (const float*)d_in[5];
  const float* W_lin = (const float*)d_in[6];
  const float* b_lin = (const float*)d_in[7];
  float* out = (float*)d_out;

  unsigned short* Apk    = (unsigned short*)d_ws;                 // 512*512 bf16
  unsigned short* WihPk  = Apk + (size_t)H_DIM * H_DIM;           // 512*64
  unsigned short* WlinPk = WihPk + (size_t)H_DIM * N_IN;          // 64*512

  pack_kernel<<<34, 256, 0, stream>>>(W_ih, W_hh, omega, W_lin, Apk, WihPk, WlinPk);
  rnn_kernel<<<(T_LEN / L_CH) * 2, 1024, 0, stream>>>(u, b_ih, b_hh, b_lin,
                                                      Apk, WihPk, WlinPk, out);
}